// Round 5
// baseline (785.926 us; speedup 1.0000x reference)
//
#include <hip/hip_runtime.h>

typedef unsigned short u16;
typedef short bf16x8 __attribute__((ext_vector_type(8)));
typedef float f32x4 __attribute__((ext_vector_type(4)));

#define EPSV 1e-3f

__device__ __forceinline__ float bf2f(u16 u) {
  union { unsigned int i; float f; } x; x.i = ((unsigned int)u) << 16; return x.f;
}
__device__ __forceinline__ u16 f2bf(float f) {
  union { float f; unsigned int i; } x; x.f = f;
  unsigned int r = x.i + 0x7fffu + ((x.i >> 16) & 1u);   // RNE
  return (u16)(r >> 16);
}

// wave-internal LDS handoff fence: drain DS pipe + stop compiler reordering
#define WAVE_FENCE() do { __builtin_amdgcn_s_waitcnt(0); __builtin_amdgcn_wave_barrier(); } while (0)

// ---------------------------------------------------------------------------
// Weight transform: fw (2,64,128,3,3) f32 -> fwT [set][ky*3+kx][co][ci] bf16
// ---------------------------------------------------------------------------
__global__ void twt_kernel(const float* __restrict__ fw, u16* __restrict__ fwT) {
  int i = blockIdx.x * blockDim.x + threadIdx.x;
  if (i >= 2 * 9 * 64 * 128) return;
  int ci = i & 127;
  int r = i >> 7;
  int co = r & 63; r >>= 6;
  int kyx = r % 9;
  int set = r / 9;
  fwT[i] = f2bf(fw[(((set * 64 + co) * 128 + ci) * 9) + kyx]);
}

// ---------------------------------------------------------------------------
// VFE via MFMA, ALL scales in one launch (block -> scale by blockIdx range).
// One wave per voxel (4 waves/block, private LDS regions).
// ---------------------------------------------------------------------------
__global__ __launch_bounds__(256, 2) void vfe_all_kernel(
    const float* __restrict__ vox0, const float* __restrict__ vox1, const float* __restrict__ vox2,
    const int* __restrict__ np0, const int* __restrict__ np1, const int* __restrict__ np2,
    const float* __restrict__ W1g, const float* __restrict__ G1, const float* __restrict__ B1,
    const float* __restrict__ RM1, const float* __restrict__ RV1,
    const float* __restrict__ W2g, const float* __restrict__ G2, const float* __restrict__ B2,
    const float* __restrict__ RM2, const float* __restrict__ RV2,
    float* __restrict__ vf0, float* __restrict__ vf1, float* __restrict__ vf2,
    int nb0, int nb1, int nb2, int N0, int N1, int N2)
{
  struct PerWave {
    u16 X[32 * 72];   // h1 bf16 [t][j], stride 72
    u16 F[32 * 40];   // feat bf16 [t][k], stride 40
    u16 G[64];        // gmax1 bf16
  };
  __shared__ __align__(16) union {
    struct { u16 W1T[64 * 40]; u16 W2T[64 * 136]; } w;
    PerWave r[4];
  } lds;

  const int tid = threadIdx.x;
  const int lane = tid & 63;
  const int wv = tid >> 6;
  const int m16 = lane & 15;
  const int q = lane >> 4;

  // scale select (wave-uniform)
  int bid = blockIdx.x;
  int s, lbid, nb, N;
  const float* vox; const int* npts; float* vf;
  if (bid < nb0)            { s = 0; lbid = bid;             nb = nb0; vox = vox0; npts = np0; vf = vf0; N = N0; }
  else if (bid < nb0 + nb1) { s = 1; lbid = bid - nb0;       nb = nb1; vox = vox1; npts = np1; vf = vf1; N = N1; }
  else                      { s = 2; lbid = bid - nb0 - nb1; nb = nb2; vox = vox2; npts = np2; vf = vf2; N = N2; }
  const float* w1 = W1g + s * 9 * 64;
  const float* g1 = G1 + s * 64;  const float* b1 = B1 + s * 64;
  const float* rm1 = RM1 + s * 64; const float* rv1 = RV1 + s * 64;
  const float* w2 = W2g + s * 128 * 64;
  const float* g2 = G2 + s * 64;  const float* b2 = B2 + s * 64;
  const float* rm2 = RM2 + s * 64; const float* rv2 = RV2 + s * 64;

  for (int i = tid; i < 64 * 40; i += 256) {
    int c = i / 40, k = i % 40;
    lds.w.W1T[i] = f2bf(k < 9 ? w1[k * 64 + c] : 0.f);
  }
  for (int i = tid; i < 64 * 136; i += 256) {
    int c = i / 136, j = i % 136;
    lds.w.W2T[i] = f2bf(j < 128 ? w2[j * 64 + c] : 0.f);
  }
  __syncthreads();

  bf16x8 bW1[4], bLo[4][2], bHi[4][2];
  float sc1[4], sh1[4], sc2[4], sh2[4];
#pragma unroll
  for (int nf = 0; nf < 4; ++nf) {
    int c = nf * 16 + m16;
    bW1[nf] = *(const bf16x8*)&lds.w.W1T[c * 40 + q * 8];
#pragma unroll
    for (int ks = 0; ks < 2; ++ks) {
      bLo[nf][ks] = *(const bf16x8*)&lds.w.W2T[c * 136 + ks * 32 + q * 8];
      bHi[nf][ks] = *(const bf16x8*)&lds.w.W2T[c * 136 + 64 + ks * 32 + q * 8];
    }
    float s1 = g1[c] * rsqrtf(rv1[c] + EPSV);
    sc1[nf] = s1; sh1[nf] = b1[c] - rm1[c] * s1;
    float s2 = g2[c] * rsqrtf(rv2[c] + EPSV);
    sc2[nf] = s2; sh2[nf] = b2[c] - rm2[c] * s2;
  }
  __syncthreads();

  u16* X = lds.r[wv].X;
  u16* F = lds.r[wv].F;
  u16* G = lds.r[wv].G;
  for (int i = lane; i < 640; i += 64) ((unsigned int*)F)[i] = 0u;

  const int wgid = lbid * 4 + wv;
  const int wstride = nb * 4;

  for (int v = wgid; v < N; v += wstride) {
    const int n = npts[v];
    float px = 0.f, py = 0.f, pz = 0.f, pw = 0.f;
    if (lane < 32) {
      float4 u = *(const float4*)(vox + ((size_t)v * 32 + lane) * 4);
      px = u.x; py = u.y; pz = u.z; pw = u.w;
    }
    float sx = px, sy = py, sz = pz;
#pragma unroll
    for (int off = 32; off >= 1; off >>= 1) {
      sx += __shfl_xor(sx, off);
      sy += __shfl_xor(sy, off);
      sz += __shfl_xor(sz, off);
    }
    float nf_ = (float)n;
    float mx = sx / nf_, my = sy / nf_, mz = sz / nf_;
    if (lane < 32) {
      float dx = px - mx, dy = py - my, dz = pz - mz;
      bf16x8 r0, r1;
      r0[0] = (short)f2bf(px); r0[1] = (short)f2bf(py);
      r0[2] = (short)f2bf(pz); r0[3] = (short)f2bf(pw);
      r0[4] = (short)f2bf(dx); r0[5] = (short)f2bf(dy);
      r0[6] = (short)f2bf(dz); r0[7] = (short)f2bf(dx);
      r1 = (bf16x8){0, 0, 0, 0, 0, 0, 0, 0};
      r1[0] = (short)f2bf(dy);
      *(bf16x8*)&F[lane * 40 + 0] = r0;
      *(bf16x8*)&F[lane * 40 + 8] = r1;
    }
    WAVE_FENCE();

    bf16x8 a1[2];
    a1[0] = *(const bf16x8*)&F[m16 * 40 + q * 8];
    a1[1] = *(const bf16x8*)&F[(16 + m16) * 40 + q * 8];
    f32x4 acc1[2][4];
#pragma unroll
    for (int mf = 0; mf < 2; ++mf)
#pragma unroll
      for (int nf = 0; nf < 4; ++nf) {
        acc1[mf][nf] = (f32x4){0.f, 0.f, 0.f, 0.f};
        acc1[mf][nf] = __builtin_amdgcn_mfma_f32_16x16x32_bf16(a1[mf], bW1[nf], acc1[mf][nf], 0, 0, 0);
      }

    float gmx[4] = {0.f, 0.f, 0.f, 0.f};
#pragma unroll
    for (int mf = 0; mf < 2; ++mf)
#pragma unroll
      for (int nf = 0; nf < 4; ++nf)
#pragma unroll
        for (int r = 0; r < 4; ++r) {
          float h = fmaxf(acc1[mf][nf][r] * sc1[nf] + sh1[nf], 0.f);
          gmx[nf] = fmaxf(gmx[nf], h);
          int t = mf * 16 + q * 4 + r;
          X[t * 72 + nf * 16 + m16] = f2bf(h);
        }
#pragma unroll
    for (int nf = 0; nf < 4; ++nf) {
      gmx[nf] = fmaxf(gmx[nf], __shfl_xor(gmx[nf], 16));
      gmx[nf] = fmaxf(gmx[nf], __shfl_xor(gmx[nf], 32));
    }
    if (q == 0) {
#pragma unroll
      for (int nf = 0; nf < 4; ++nf) G[nf * 16 + m16] = f2bf(gmx[nf]);
    }
    WAVE_FENCE();

    f32x4 ga[4];
#pragma unroll
    for (int nf = 0; nf < 4; ++nf) ga[nf] = (f32x4){0.f, 0.f, 0.f, 0.f};
#pragma unroll
    for (int ks = 0; ks < 2; ++ks) {
      bf16x8 ag = (bf16x8){0, 0, 0, 0, 0, 0, 0, 0};
      if (m16 == 0) ag = *(const bf16x8*)&G[ks * 32 + q * 8];
#pragma unroll
      for (int nf = 0; nf < 4; ++nf)
        ga[nf] = __builtin_amdgcn_mfma_f32_16x16x32_bf16(ag, bHi[nf][ks], ga[nf], 0, 0, 0);
    }
    float gt[4];
#pragma unroll
    for (int nf = 0; nf < 4; ++nf) {
      float s_ = ga[nf][0] + ga[nf][1] + ga[nf][2] + ga[nf][3];
      s_ += __shfl_xor(s_, 16);
      s_ += __shfl_xor(s_, 32);
      gt[nf] = s_;
    }

    f32x4 acc2[2][4];
#pragma unroll
    for (int mf = 0; mf < 2; ++mf)
#pragma unroll
      for (int nf = 0; nf < 4; ++nf)
        acc2[mf][nf] = (f32x4){gt[nf], gt[nf], gt[nf], gt[nf]};
#pragma unroll
    for (int ks = 0; ks < 2; ++ks) {
      bf16x8 a2[2];
      a2[0] = *(const bf16x8*)&X[m16 * 72 + ks * 32 + q * 8];
      a2[1] = *(const bf16x8*)&X[(16 + m16) * 72 + ks * 32 + q * 8];
#pragma unroll
      for (int mf = 0; mf < 2; ++mf)
#pragma unroll
        for (int nf = 0; nf < 4; ++nf)
          acc2[mf][nf] = __builtin_amdgcn_mfma_f32_16x16x32_bf16(a2[mf], bLo[nf][ks], acc2[mf][nf], 0, 0, 0);
    }

    float vm[4] = {0.f, 0.f, 0.f, 0.f};
#pragma unroll
    for (int mf = 0; mf < 2; ++mf)
#pragma unroll
      for (int nf = 0; nf < 4; ++nf)
#pragma unroll
        for (int r = 0; r < 4; ++r) {
          int t = mf * 16 + q * 4 + r;
          float h2 = fmaxf(acc2[mf][nf][r] * sc2[nf] + sh2[nf], 0.f);
          if (t < n) vm[nf] = fmaxf(vm[nf], h2);
        }
#pragma unroll
    for (int nf = 0; nf < 4; ++nf) {
      vm[nf] = fmaxf(vm[nf], __shfl_xor(vm[nf], 16));
      vm[nf] = fmaxf(vm[nf], __shfl_xor(vm[nf], 32));
    }
    float outv = (q == 0) ? vm[0] : (q == 1) ? vm[1] : (q == 2) ? vm[2] : vm[3];
    vf[(size_t)v * 64 + q * 16 + m16] = outv;
    __builtin_amdgcn_wave_barrier();
  }
}

// ---------------------------------------------------------------------------
// Scatter pass 1 (all scales, one launch): last-write-wins == max voxel index
// ---------------------------------------------------------------------------
__global__ void winner_all_kernel(
    const int* __restrict__ c0, const int* __restrict__ c1, const int* __restrict__ c2,
    int* __restrict__ w0, int* __restrict__ w1, int* __restrict__ w2,
    int N0, int N1, int N2) {
  int i = blockIdx.x * blockDim.x + threadIdx.x;
  const int* co; int* wn; int H, W, v;
  if (i < N0) { co = c0; wn = w0; H = 496; W = 432; v = i; }
  else if (i < N0 + N1) { co = c1; wn = w1; H = 248; W = 216; v = i - N0; }
  else if (i < N0 + N1 + N2) { co = c2; wn = w2; H = 124; W = 108; v = i - N0 - N1; }
  else return;
  int b = co[v * 4 + 0];
  int y = min(max(co[v * 4 + 2], 0), H - 1);
  int x = min(max(co[v * 4 + 3], 0), W - 1);
  atomicMax(&wn[(b * H + y) * W + x], v);
}

// ---------------------------------------------------------------------------
// Scatter pass 2 + zero-fill (only for g2b now), thread = 8 channels.
// ---------------------------------------------------------------------------
__global__ void fill_kernel(const int* __restrict__ win, const float* __restrict__ vf,
                            u16* __restrict__ dst, int cells, int cstride) {
  int i = blockIdx.x * blockDim.x + threadIdx.x;
  if (i >= cells * 8) return;
  int cell = i >> 3, c8 = (i & 7) * 8;
  int wv = win[cell];
  bf16x8 o = (bf16x8){0, 0, 0, 0, 0, 0, 0, 0};
  if (wv >= 0) {
    const float* p = vf + (size_t)wv * 64 + c8;
    float4 v0 = *(const float4*)p;
    float4 v1 = *(const float4*)(p + 4);
    o[0] = (short)f2bf(v0.x); o[1] = (short)f2bf(v0.y);
    o[2] = (short)f2bf(v0.z); o[3] = (short)f2bf(v0.w);
    o[4] = (short)f2bf(v1.x); o[5] = (short)f2bf(v1.y);
    o[6] = (short)f2bf(v1.z); o[7] = (short)f2bf(v1.w);
  }
  *(bf16x8*)&dst[(size_t)cell * cstride + c8] = o;
}

// ---------------------------------------------------------------------------
// Bilinear tap helper: 8 channels at (y,x) of the 2x-upsampled (2Hc,2Wc) grid
// from src NHWC-64 bf16. jax.image.resize half-pixel -> edge weights .25/.75.
// ---------------------------------------------------------------------------
template<int Hc, int Wc>
__device__ __forceinline__ bf16x8 bilerp8(const u16* __restrict__ src, int n, int y, int x, int cis) {
  int ky = y >> 1, kx = x >> 1;
  int ya, yb, xa, xb; float wya, wxa;
  if ((y & 1) == 0) { ya = ky > 0 ? ky - 1 : 0; yb = ky; wya = 0.25f; }
  else              { ya = ky; yb = (ky + 1 < Hc) ? ky + 1 : Hc - 1; wya = 0.75f; }
  if ((x & 1) == 0) { xa = kx > 0 ? kx - 1 : 0; xb = kx; wxa = 0.25f; }
  else              { xa = kx; xb = (kx + 1 < Wc) ? kx + 1 : Wc - 1; wxa = 0.75f; }
  float wyb = 1.f - wya, wxb = 1.f - wxa;
  const u16* sp = src + cis;
  bf16x8 vaa = *(const bf16x8*)&sp[((size_t)(n * Hc + ya) * Wc + xa) * 64];
  bf16x8 vab = *(const bf16x8*)&sp[((size_t)(n * Hc + ya) * Wc + xb) * 64];
  bf16x8 vba = *(const bf16x8*)&sp[((size_t)(n * Hc + yb) * Wc + xa) * 64];
  bf16x8 vbb = *(const bf16x8*)&sp[((size_t)(n * Hc + yb) * Wc + xb) * 64];
  bf16x8 o;
#pragma unroll
  for (int j = 0; j < 8; ++j) {
    float v = wya * (wxa * bf2f((u16)vaa[j]) + wxb * bf2f((u16)vab[j])) +
              wyb * (wxa * bf2f((u16)vba[j]) + wxb * bf2f((u16)vbb[j]));
    o[j] = (short)f2bf(v);
  }
  return o;
}

// ---------------------------------------------------------------------------
// FUSED Conv3x3 + BN + ReLU, implicit GEMM with bf16 MFMA 16x16x32.
// Input is built on the fly into the LDS A-tile:
//   ci 0..63  (hf=0): scatter-gather  win[cell] -> vf row (or 0)
//   ci 64..127(hf=1): bilinear 2x upsample of upsrc (NHWC-64 bf16)
// Block: 256 thr (4 waves). Wave = 2 rows x 32 px x 64 co -> 4x4 frags.
// B per-tap double-buffered -> 1 barrier/tap. LDS 67.4 KB -> 2 blk/CU.
// ---------------------------------------------------------------------------
template<int H, int W, bool NCHW_OUT>
__global__ __launch_bounds__(256, 2) void conv_kernel(
    const int* __restrict__ win, const float* __restrict__ vfsrc,
    const u16* __restrict__ upsrc, const u16* __restrict__ wT,
    const float* __restrict__ fg, const float* __restrict__ fb,
    const float* __restrict__ fm, const float* __restrict__ fv,
    void* __restrict__ outv)
{
  constexpr int XT = 32, YT = 8;
  constexpr int XTILES = (W + XT - 1) / XT;
  constexpr int CIP = 72;                      // 64-ci half + 8 pad (u16)
  constexpr int NPX = 10 * 34;                 // halo positions
  __shared__ __align__(16) union {
    struct { u16 A[NPX * CIP]; u16 B[2][64 * CIP]; } s;
    float T[4 * 64 * 33];                      // epilogue transpose (NCHW path)
  } lds;

  const int tid = threadIdx.x;
  const int lane = tid & 63;
  const int wv = tid >> 6;                     // wave id -> rows [2wv, 2wv+1]
  const int m16 = lane & 15;
  const int q = lane >> 4;

  int bid = blockIdx.x;
  const int xt = bid % XTILES; bid /= XTILES;
  const int yt = bid % (H / YT);
  const int n = bid / (H / YT);
  const int x0 = xt * XT, y0 = yt * YT;

  float sc[4], sh[4];
#pragma unroll
  for (int nf = 0; nf < 4; ++nf) {
    int co = nf * 16 + m16;
    float s = fg[co] * rsqrtf(fv[co] + EPSV);
    sc[nf] = s;
    sh[nf] = fb[co] - fm[co] * s;
  }

  f32x4 acc[4][4];
#pragma unroll
  for (int mf = 0; mf < 4; ++mf)
#pragma unroll
    for (int nf = 0; nf < 4; ++nf)
      acc[mf][nf] = (f32x4){0.f, 0.f, 0.f, 0.f};

  for (int hf = 0; hf < 2; ++hf) {
    // ---- build A half in LDS: 340 halo px x 64 ci (fused source) ----
    {
      const int cis = (tid & 7) * 8;
#pragma unroll
      for (int it = 0; it < 11; ++it) {
        int p = (tid >> 3) + it * 32;
        if (p < NPX) {
          int r = p / 34, xx = p - r * 34;
          int gy = y0 - 1 + r, gx = x0 - 1 + xx;
          bf16x8 o = (bf16x8){0, 0, 0, 0, 0, 0, 0, 0};
          if (gy >= 0 && gy < H && gx >= 0 && gx < W) {
            if (hf == 0) {
              int wvx = win[(n * H + gy) * W + gx];
              if (wvx >= 0) {
                const float* pv = vfsrc + (size_t)wvx * 64 + cis;
                float4 v0 = *(const float4*)pv;
                float4 v1 = *(const float4*)(pv + 4);
                o[0] = (short)f2bf(v0.x); o[1] = (short)f2bf(v0.y);
                o[2] = (short)f2bf(v0.z); o[3] = (short)f2bf(v0.w);
                o[4] = (short)f2bf(v1.x); o[5] = (short)f2bf(v1.y);
                o[6] = (short)f2bf(v1.z); o[7] = (short)f2bf(v1.w);
              }
            } else {
              o = bilerp8<H / 2, W / 2>(upsrc, n, gy, gx, cis);
            }
          }
          *(bf16x8*)&lds.s.A[p * CIP + cis] = o;
        }
      }
    }
    // stage B for tap 0 into buffer 0
    {
#pragma unroll
      for (int it = 0; it < 2; ++it) {
        int e8 = (it * 256 + tid) * 8;
        int co = e8 >> 6, ci = e8 & 63;
        uint4 v = *(const uint4*)(wT + (co * 128 + hf * 64 + ci));
        *(uint4*)&lds.s.B[0][co * CIP + ci] = v;
      }
    }
    __syncthreads();

    for (int kyx = 0; kyx < 9; ++kyx) {
      if (kyx < 8) {   // prefetch next tap's B into the other buffer
#pragma unroll
        for (int it = 0; it < 2; ++it) {
          int e8 = (it * 256 + tid) * 8;
          int co = e8 >> 6, ci = e8 & 63;
          uint4 v = *(const uint4*)(wT + ((kyx + 1) * 8192 + co * 128 + hf * 64 + ci));
          *(uint4*)&lds.s.B[(kyx + 1) & 1][co * CIP + ci] = v;
        }
      }
      const int ky = kyx / 3, kx = kyx - ky * 3;
      const u16* Bb = lds.s.B[kyx & 1];
#pragma unroll
      for (int cc = 0; cc < 2; ++cc) {
        bf16x8 a[4], b[4];
#pragma unroll
        for (int mf = 0; mf < 4; ++mf) {
          int p = (wv * 2 + (mf >> 1) + ky) * 34 + (mf & 1) * 16 + m16 + kx;
          a[mf] = *(const bf16x8*)&lds.s.A[p * CIP + cc * 32 + q * 8];
        }
#pragma unroll
        for (int nf = 0; nf < 4; ++nf)
          b[nf] = *(const bf16x8*)&Bb[(nf * 16 + m16) * CIP + cc * 32 + q * 8];
#pragma unroll
        for (int mf = 0; mf < 4; ++mf)
#pragma unroll
          for (int nf = 0; nf < 4; ++nf)
            acc[mf][nf] = __builtin_amdgcn_mfma_f32_16x16x32_bf16(a[mf], b[nf], acc[mf][nf], 0, 0, 0);
      }
      __syncthreads();   // B[(kyx+1)&1] visible; A/B reads of this tap done
    }
  }

  if (!NCHW_OUT) {
    // NHWC(64) bf16 direct store (internal fused1 buffer)
    u16* out = (u16*)outv;
#pragma unroll
    for (int mf = 0; mf < 4; ++mf) {
      int y = y0 + wv * 2 + (mf >> 1);
#pragma unroll
      for (int nf = 0; nf < 4; ++nf)
#pragma unroll
        for (int r = 0; r < 4; ++r) {
          int px = (mf & 1) * 16 + q * 4 + r;
          int x = x0 + px;
          if (x < W) {
            int co = nf * 16 + m16;
            float v = fmaxf(acc[mf][nf][r] * sc[nf] + sh[nf], 0.f);
            out[((size_t)(n * H + y) * W + x) * 64 + co] = f2bf(v);
          }
        }
    }
  } else {
    // NCHW f32 d_out: per-row transpose via wave-private LDS region
    float* out = (float*)outv;
    float* T = &lds.T[wv * 64 * 33];
#pragma unroll
    for (int yr = 0; yr < 2; ++yr) {
#pragma unroll
      for (int xc = 0; xc < 2; ++xc)
#pragma unroll
        for (int nf = 0; nf < 4; ++nf)
#pragma unroll
          for (int r = 0; r < 4; ++r) {
            int px = xc * 16 + q * 4 + r;
            int co = nf * 16 + m16;
            T[co * 33 + px] = fmaxf(acc[yr * 2 + xc][nf][r] * sc[nf] + sh[nf], 0.f);
          }
      WAVE_FENCE();
      const int px = lane & 31, co2 = lane >> 5;
      const int y = y0 + wv * 2 + yr;
      int x = x0 + px;
#pragma unroll 4
      for (int it = 0; it < 32; ++it) {
        int co = it * 2 + co2;
        float v = T[co * 33 + px];
        if (x < W) out[((size_t)(n * 64 + co) * H + y) * W + x] = v;
      }
      WAVE_FENCE();
    }
  }
}

// ---------------------------------------------------------------------------
extern "C" void kernel_launch(void* const* d_in, const int* in_sizes, int n_in,
                              void* d_out, int out_size, void* d_ws, size_t ws_size,
                              hipStream_t stream) {
  int I_vox[3], I_np[3], I_co[3];
  int I_w1, I_g1, I_b1, I_rm1, I_rv1, I_w2, I_g2, I_b2, I_rm2, I_rv2;
  int I_fw, I_fg, I_fb, I_fm, I_fv;
  if (in_sizes[1] == 40000) {
    I_vox[0] = 0; I_np[0] = 1; I_co[0] = 2;
    I_vox[1] = 3; I_np[1] = 4; I_co[1] = 5;
    I_vox[2] = 6; I_np[2] = 7; I_co[2] = 8;
    I_w1 = 9; I_g1 = 10; I_b1 = 11; I_rm1 = 12; I_rv1 = 13;
    I_w2 = 14; I_g2 = 15; I_b2 = 16; I_rm2 = 17; I_rv2 = 18;
    I_fw = 19; I_fg = 20; I_fb = 21; I_fm = 22; I_fv = 23;
  } else {
    I_vox[0] = 0; I_vox[1] = 1; I_vox[2] = 2;
    I_w1 = 3; I_g1 = 4; I_b1 = 5; I_rm1 = 6; I_rv1 = 7;
    I_w2 = 8; I_g2 = 9; I_b2 = 10; I_rm2 = 11; I_rv2 = 12;
    I_fw = 13; I_fg = 14; I_fb = 15; I_fm = 16; I_fv = 17;
    I_np[0] = 18; I_np[1] = 19; I_np[2] = 20;
    I_co[0] = 21; I_co[1] = 22; I_co[2] = 23;
  }

  const int HS[3] = {496, 248, 124};
  const int WS[3] = {432, 216, 108};
  int Nv[3];
  for (int s = 0; s < 3; ++s) Nv[s] = in_sizes[I_np[s]];

  char* wsp = (char*)d_ws;
  size_t off = 0;
  auto take = [&](size_t bytes) -> void* {
    void* p = wsp + off;
    off = (off + bytes + 255) & ~(size_t)255;
    return p;
  };
  float* vf[3];
  for (int s = 0; s < 3; ++s) vf[s] = (float*)take((size_t)Nv[s] * 64 * 4);
  int cells[3];
  for (int s = 0; s < 3; ++s) cells[s] = 4 * HS[s] * WS[s];
  size_t winbytes = ((size_t)cells[0] + cells[1] + cells[2]) * 4;
  int* win0 = (int*)take(winbytes);            // contiguous: one memset
  int* win1 = win0 + cells[0];
  int* win2 = win1 + cells[1];
  u16* g2b  = (u16*)take((size_t)cells[2] * 64 * 2);    // (4,124,108,64) NHWC bf16
  u16* fus1 = (u16*)take((size_t)cells[1] * 64 * 2);    // (4,248,216,64)
  u16* fwT  = (u16*)take((size_t)2 * 9 * 64 * 128 * 2);

  const float* W1 = (const float*)d_in[I_w1];
  const float* G1 = (const float*)d_in[I_g1];
  const float* B1 = (const float*)d_in[I_b1];
  const float* RM1 = (const float*)d_in[I_rm1];
  const float* RV1 = (const float*)d_in[I_rv1];
  const float* W2 = (const float*)d_in[I_w2];
  const float* G2 = (const float*)d_in[I_g2];
  const float* B2 = (const float*)d_in[I_b2];
  const float* RM2 = (const float*)d_in[I_rm2];
  const float* RV2 = (const float*)d_in[I_rv2];
  const float* FW = (const float*)d_in[I_fw];
  const float* FG = (const float*)d_in[I_fg];
  const float* FB = (const float*)d_in[I_fb];
  const float* FM = (const float*)d_in[I_fm];
  const float* FV = (const float*)d_in[I_fv];

  hipMemsetAsync(win0, 0xFF, winbytes, stream);

  twt_kernel<<<(2 * 9 * 64 * 128 + 255) / 256, 256, 0, stream>>>(FW, fwT);

  int nb[3];
  for (int s = 0; s < 3; ++s) {
    nb[s] = (Nv[s] + 3) / 4;
    if (nb[s] > 1024) nb[s] = 1024;
  }
  vfe_all_kernel<<<nb[0] + nb[1] + nb[2], 256, 0, stream>>>(
      (const float*)d_in[I_vox[0]], (const float*)d_in[I_vox[1]], (const float*)d_in[I_vox[2]],
      (const int*)d_in[I_np[0]], (const int*)d_in[I_np[1]], (const int*)d_in[I_np[2]],
      W1, G1, B1, RM1, RV1, W2, G2, B2, RM2, RV2,
      vf[0], vf[1], vf[2],
      nb[0], nb[1], nb[2], Nv[0], Nv[1], Nv[2]);

  winner_all_kernel<<<(Nv[0] + Nv[1] + Nv[2] + 255) / 256, 256, 0, stream>>>(
      (const int*)d_in[I_co[0]], (const int*)d_in[I_co[1]], (const int*)d_in[I_co[2]],
      win0, win1, win2, Nv[0], Nv[1], Nv[2]);

  fill_kernel<<<(cells[2] * 8 + 255) / 256, 256, 0, stream>>>(win2, vf[2], g2b, cells[2], 64);

  conv_kernel<248, 216, false><<<4 * (248 / 8) * 7, 256, 0, stream>>>(
      win1, vf[1], g2b, fwT + 9 * 64 * 128, FG + 64, FB + 64, FM + 64, FV + 64, fus1);

  conv_kernel<496, 432, true><<<4 * (496 / 8) * 14, 256, 0, stream>>>(
      win0, vf[0], fus1, fwT, FG, FB, FM, FV, (float*)d_out);
}